// Round 9
// baseline (749.332 us; speedup 1.0000x reference)
//
#include <hip/hip_runtime.h>
#include <stdint.h>

#define BATCH  4
#define SQ     2048
#define DMODEL 512
#define NH     8
#define DK     64

typedef __attribute__((ext_vector_type(8))) short short8;
typedef __attribute__((ext_vector_type(4))) float f32x4;

// ---------------- threefry2x32 (JAX-compatible, 20 rounds) ----------------
struct TFK { uint32_t a, b; };
constexpr uint32_t rotl_ce(uint32_t x, int d) {
  return (x << d) | (x >> (32 - d));
}
constexpr TFK tf_ce(uint32_t k0, uint32_t k1, uint32_t x0, uint32_t x1) {
  const uint32_t ks[3] = {k0, k1, k0 ^ k1 ^ 0x1BD11BDAu};
  const int rot[2][4] = {{13, 15, 26, 6}, {17, 29, 16, 24}};
  x0 += k0; x1 += k1;
  for (int c = 0; c < 5; ++c) {
    for (int j = 0; j < 4; ++j) {
      x0 += x1; x1 = rotl_ce(x1, rot[c & 1][j]); x1 ^= x0;
    }
    x0 += ks[(c + 1) % 3];
    x1 += ks[(c + 2) % 3] + (uint32_t)(c + 1);
  }
  return TFK{x0, x1};
}
constexpr TFK SPK = tf_ce(0u, 42u, 0u, 1u);  // fold_in(key(42), 1)
constexpr TFK DPK = tf_ce(0u, 42u, 0u, 2u);  // fold_in(key(42), 2)

#define SP_THR 0x80000200u
#define DP_THR 0x1999A200u

// Key-schedule constants as kernel args (SGPR-resident).
struct TfArgs {
  uint32_t sp[8];
  uint32_t dp[8];
  uint32_t sp_thr, dp_thr;
};

__device__ __forceinline__ void tf_round(uint32_t &x0, uint32_t &x1, int d) {
  x0 += x1;
  x1 = __builtin_amdgcn_alignbit(x1, x1, 32 - d);
  x1 ^= x0;
}
__device__ __forceinline__ void tf_grp(uint32_t &x0, uint32_t &x1,
                                       uint32_t injx1, uint32_t injx0, int d0,
                                       int d1, int d2, int d3) {
  x1 += injx1;
  x0 = x0 + injx0 + x1;
  x1 = __builtin_amdgcn_alignbit(x1, x1, 32 - d0);
  x1 ^= x0;
  tf_round(x0, x1, d1);
  tf_round(x0, x1, d2);
  tf_round(x0, x1, d3);
}
__device__ __forceinline__ uint32_t tf_rt(const uint32_t *__restrict__ c,
                                          uint32_t ctr) {
  uint32_t x1 = c[1] + ctr;
  uint32_t x0 = c[0] + x1;
  x1 = __builtin_amdgcn_alignbit(x1, x1, 19);
  x1 ^= x0;
  tf_round(x0, x1, 15);
  tf_round(x0, x1, 26);
  tf_round(x0, x1, 6);
  tf_grp(x0, x1, c[2], c[1], 17, 29, 16, 24);
  tf_grp(x0, x1, c[3], c[7], 13, 15, 26, 6);
  tf_grp(x0, x1, c[4], c[0], 17, 29, 16, 24);
  tf_grp(x0, x1, c[5], c[1], 13, 15, 26, 6);
  return (x0 + c[7]) ^ (x1 + c[6]);
}

__device__ __forceinline__ ushort f2bf_rne(float f) {
  uint32_t u = __float_as_uint(f);
  return (ushort)((u + 0x7fffu + ((u >> 16) & 1u)) >> 16);
}
__device__ __forceinline__ float bf2f(ushort h) {
  return __uint_as_float((uint32_t)h << 16);
}
__device__ __forceinline__ float exp_scaled(float s) {  // exp(s/8)
#if __has_builtin(__builtin_amdgcn_exp2f)
  return __builtin_amdgcn_exp2f(s * 0.18033688011112042f);
#else
  return __expf(s * 0.125f);
#endif
}
// packed RNE f32->bf16x2 (same rounding as f2bf_rne)
__device__ __forceinline__ uint32_t cvt_pk_bf16(float a, float b) {
  uint32_t r;
  asm("v_cvt_pk_bf16_f32 %0, %1, %2" : "=v"(r) : "v"(a), "v"(b));
  return r;
}

// ---------------- hi/lo split: q,k,v + 4 weights in ONE kernel --------------
__device__ __forceinline__ void split4(const float *__restrict__ src,
                                       ushort *__restrict__ dh,
                                       ushort *__restrict__ dl, size_t base) {
  float4 x = *(const float4 *)(src + base);
  uint32_t h[4], lo[4];
#pragma unroll
  for (int i = 0; i < 4; ++i) {
    float xi = ((const float *)&x)[i];
    ushort hh = f2bf_rne(xi);
    h[i] = hh;
    lo[i] = f2bf_rne(xi - bf2f(hh));
  }
  uint2 ph, pl;
  ph.x = h[0] | (h[1] << 16);  ph.y = h[2] | (h[3] << 16);
  pl.x = lo[0] | (lo[1] << 16); pl.y = lo[2] | (lo[3] << 16);
  *(uint2 *)(dh + base) = ph;
  *(uint2 *)(dl + base) = pl;
}

__global__ __launch_bounds__(256) void split_all(
    const float *__restrict__ q, const float *__restrict__ k,
    const float *__restrict__ v, const float *__restrict__ Wq,
    const float *__restrict__ Wk, const float *__restrict__ Wv,
    const float *__restrict__ Wo, ushort *__restrict__ qh,
    ushort *__restrict__ ql, ushort *__restrict__ kh, ushort *__restrict__ kl,
    ushort *__restrict__ vh, ushort *__restrict__ vl, ushort *__restrict__ Wqh,
    ushort *__restrict__ Wql, ushort *__restrict__ Wkh,
    ushort *__restrict__ Wkl, ushort *__restrict__ Wvh,
    ushort *__restrict__ Wvl, ushort *__restrict__ Woh,
    ushort *__restrict__ Wol) {
  const int bid = blockIdx.x;
  const float *src;
  ushort *dh, *dl;
  uint32_t lb;
  if (bid < 12288) {  // q,k,v: 4096 blocks each
    const int which = bid >> 12;
    lb = bid & 4095;
    src = which == 0 ? q : (which == 1 ? k : v);
    dh = which == 0 ? qh : (which == 1 ? kh : vh);
    dl = which == 0 ? ql : (which == 1 ? kl : vl);
  } else {  // weights: 256 blocks each
    const int t = bid - 12288;
    const int wsel = t >> 8;
    lb = t & 255;
    src = wsel == 0 ? Wq : (wsel == 1 ? Wk : (wsel == 2 ? Wv : Wo));
    dh = wsel == 0 ? Wqh : (wsel == 1 ? Wkh : (wsel == 2 ? Wvh : Woh));
    dl = wsel == 0 ? Wql : (wsel == 1 ? Wkl : (wsel == 2 ? Wvl : Wol));
  }
  const size_t base = ((size_t)lb * 256 + threadIdx.x) * 4;
  split4(src, dh, dl, base);
}

// ---------------- hi/lo bf16 MFMA GEMM core (BN=32 for TLP) -----------------
// D = A @ B^T (+bias); A [M][512], B [N][512], hi/lo bf16.
// Block: 128 A-rows x 32 B-rows; 4 waves of 32x32 (2x2 16x16 frags).
// MODE 0: fp32 out, bias[col].  MODE 1: bf16 out, bias[col].
// MODE 2: bf16 transposed per-head vpt out, bias[row], via LDS transpose.
template <int MODE>
__device__ __forceinline__ void proj_core(const ushort *__restrict__ Ah,
                                          const ushort *__restrict__ Al,
                                          const ushort *__restrict__ Bh,
                                          const ushort *__restrict__ Bl,
                                          const float *__restrict__ bias,
                                          void *__restrict__ Yv, int bx,
                                          int by) {
  __shared__ ushort Tt[MODE == 2 ? 128 * 40 : 1];
  const int tid = threadIdx.x;
  const int w = tid >> 6, l = tid & 63;
  const int lr = l & 15, lq = l >> 4;
  const int am = by * 128 + w * 32;
  const int bn = bx * 32;
  f32x4 acc[2][2];
#pragma unroll
  for (int i = 0; i < 2; ++i)
#pragma unroll
    for (int j = 0; j < 2; ++j) acc[i][j] = (f32x4){0.f, 0.f, 0.f, 0.f};

#pragma unroll 2
  for (int k0 = 0; k0 < DMODEL; k0 += 32) {
    short8 ah[2], al[2], bh[2], bl[2];
#pragma unroll
    for (int mf = 0; mf < 2; ++mf) {
      const size_t off = (size_t)(am + mf * 16 + lr) * DMODEL + k0 + lq * 8;
      ah[mf] = *(const short8 *)(Ah + off);
      al[mf] = *(const short8 *)(Al + off);
    }
#pragma unroll
    for (int nf = 0; nf < 2; ++nf) {
      const size_t off = (size_t)(bn + nf * 16 + lr) * DMODEL + k0 + lq * 8;
      bh[nf] = *(const short8 *)(Bh + off);
      bl[nf] = *(const short8 *)(Bl + off);
    }
#pragma unroll
    for (int mf = 0; mf < 2; ++mf)
#pragma unroll
      for (int nf = 0; nf < 2; ++nf) {
        acc[mf][nf] = __builtin_amdgcn_mfma_f32_16x16x32_bf16(
            ah[mf], bh[nf], acc[mf][nf], 0, 0, 0);
        acc[mf][nf] = __builtin_amdgcn_mfma_f32_16x16x32_bf16(
            ah[mf], bl[nf], acc[mf][nf], 0, 0, 0);
        acc[mf][nf] = __builtin_amdgcn_mfma_f32_16x16x32_bf16(
            al[mf], bh[nf], acc[mf][nf], 0, 0, 0);
      }
  }

  if (MODE == 2) {
#pragma unroll
    for (int mf = 0; mf < 2; ++mf)
#pragma unroll
      for (int nf = 0; nf < 2; ++nf) {
        const int gn2 = am + mf * 16 + lq * 4;
#pragma unroll
        for (int r = 0; r < 4; ++r) {
          const int featl = (w * 32 + mf * 16 + lq * 4 + r);
          Tt[featl * 40 + nf * 16 + lr] =
              f2bf_rne(acc[mf][nf][r] + bias[gn2 + r]);
        }
      }
    __syncthreads();
    ushort *Y = (ushort *)Yv;
    const int feat = tid >> 1, half = tid & 1;
    const int gfeat = by * 128 + feat;
    const int bcol = bn >> 11, scol = (bn & 2047) + half * 16;
    ushort *dst = Y + ((size_t)(bcol * DMODEL + gfeat)) * SQ + scol;
    const ushort *srcp = &Tt[feat * 40 + half * 16];
    *(uint4 *)(dst) = *(const uint4 *)(srcp);
    *(uint4 *)(dst + 8) = *(const uint4 *)(srcp + 8);
  } else {
#pragma unroll
    for (int mf = 0; mf < 2; ++mf)
#pragma unroll
      for (int nf = 0; nf < 2; ++nf) {
        const int gn = bn + nf * 16 + lr;
        const float bb = bias[gn];
        if (MODE == 0) {
          float *Y = (float *)Yv;
#pragma unroll
          for (int r = 0; r < 4; ++r) {
            const int gm = am + mf * 16 + lq * 4 + r;
            Y[(size_t)gm * DMODEL + gn] = acc[mf][nf][r] + bb;
          }
        } else {
          ushort *Y = (ushort *)Yv;
#pragma unroll
          for (int r = 0; r < 4; ++r) {
            const int gm = am + mf * 16 + lq * 4 + r;
            Y[(size_t)gm * DMODEL + gn] = f2bf_rne(acc[mf][nf][r] + bb);
          }
        }
      }
  }
}

// Q and K projections fused via blockIdx.z. Grid (16, 64, 2).
__global__ __launch_bounds__(256) void proj_qk(
    const ushort *__restrict__ qih, const ushort *__restrict__ qil,
    const ushort *__restrict__ kih, const ushort *__restrict__ kil,
    const ushort *__restrict__ Wqh, const ushort *__restrict__ Wql,
    const ushort *__restrict__ Wkh, const ushort *__restrict__ Wkl,
    const float *__restrict__ bq, const float *__restrict__ bk,
    ushort *__restrict__ qp, ushort *__restrict__ kp) {
  if (blockIdx.z == 0)
    proj_core<1>(qih, qil, Wqh, Wql, bq, qp, blockIdx.x, blockIdx.y);
  else
    proj_core<1>(kih, kil, Wkh, Wkl, bk, kp, blockIdx.x, blockIdx.y);
}

// V projection -> per-head V^T (A = Wv feats, B = value rows). Grid (256, 4).
__global__ __launch_bounds__(256) void proj_v(
    const ushort *__restrict__ Wvh, const ushort *__restrict__ Wvl,
    const ushort *__restrict__ vih, const ushort *__restrict__ vil,
    const float *__restrict__ bv, ushort *__restrict__ vpt) {
  proj_core<2>(Wvh, Wvl, vih, vil, bv, vpt, blockIdx.x, blockIdx.y);
}

// Output projection (fp32 out). Grid (16, 64).
__global__ __launch_bounds__(256) void proj_o(
    const ushort *__restrict__ xah, const ushort *__restrict__ xal,
    const ushort *__restrict__ Woh, const ushort *__restrict__ Wol,
    const float *__restrict__ bo, float *__restrict__ out) {
  proj_core<0>(xah, xal, Woh, Wol, bo, out, blockIdx.x, blockIdx.y);
}

// ---------------- MFMA attention, fused masks, double-buffered staging ------
__global__ __launch_bounds__(256, 4) void attn_mfma(
    const ushort *__restrict__ qp, const ushort *__restrict__ kp,
    const ushort *__restrict__ vpt, ushort *__restrict__ xah,
    ushort *__restrict__ xal, TfArgs ta) {
  __shared__ __align__(16) uint8_t lds[40960];
  const int b = blockIdx.z, h = blockIdx.y;
  const int qb = blockIdx.x * 64;
  const int tid = threadIdx.x;
  const int w = tid >> 6, l = tid & 63;
  const int lr = l & 15, lq = l >> 4;
  uint8_t *Ps = lds + 32768 + w * 2048;
  const int bh = b * NH + h;

  short8 qf[2];
  {
    const int qrow = qb + w * 16 + lr;
    const ushort *qrowp = qp + ((size_t)(b * SQ + qrow)) * DMODEL + h * DK;
    qf[0] = *(const short8 *)(qrowp + lq * 8);
    qf[1] = *(const short8 *)(qrowp + 32 + lq * 8);
  }
  f32x4 o[4];
  f32x4 lacc;
#pragma unroll
  for (int nd = 0; nd < 4; ++nd) o[nd] = (f32x4){0.f, 0.f, 0.f, 0.f};
  lacc = (f32x4){0.f, 0.f, 0.f, 0.f};

  uint32_t rowflat[4];
#pragma unroll
  for (int r = 0; r < 4; ++r)
    rowflat[r] = ((uint32_t)(bh * SQ + qb + w * 16 + lq * 4 + r)) << 11;

  const int srow = tid >> 2;
  const int sc0 = (tid & 3) * 2;
  const int ssw = (srow & 7) << 4;
  const ushort *kbase =
      kp + ((size_t)(b * SQ) + srow) * DMODEL + h * DK + sc0 * 8;
  const ushort *vbase = vpt + ((size_t)(bh * DK + srow)) * SQ + sc0 * 8;
  const int la0 = (srow * 128 + sc0 * 16) ^ ssw;
  const int la1 = (srow * 128 + (sc0 + 1) * 16) ^ ssw;

  uint4 kr0, kr1, vr0, vr1;
#define ISSUE(kv_)                                            \
  {                                                           \
    const ushort *ks_ = kbase + (size_t)(kv_)*DMODEL;         \
    kr0 = *(const uint4 *)ks_;                                \
    kr1 = *(const uint4 *)(ks_ + 8);                          \
    const ushort *vs_ = vbase + (kv_);                        \
    vr0 = *(const uint4 *)vs_;                                \
    vr1 = *(const uint4 *)(vs_ + 8);                          \
  }
#define STORE(buf_)                                           \
  {                                                           \
    uint8_t *Kb_ = lds + (buf_)*8192;                         \
    uint8_t *Vb_ = lds + 16384 + (buf_)*8192;                 \
    *(uint4 *)(Kb_ + la0) = kr0;                              \
    *(uint4 *)(Kb_ + la1) = kr1;                              \
    *(uint4 *)(Vb_ + la0) = vr0;                              \
    *(uint4 *)(Vb_ + la1) = vr1;                              \
  }

  ISSUE(0)
  STORE(0)
  __syncthreads();

  for (int kv = 0; kv < SQ; kv += 64) {
    const int cur = (kv >> 6) & 1;
    uint8_t *Ks = lds + cur * 8192;
    uint8_t *Vt = lds + 16384 + cur * 8192;
    const bool more = (kv + 64) < SQ;
    if (more) ISSUE(kv + 64)

    f32x4 s[4];
#pragma unroll
    for (int ni = 0; ni < 4; ++ni) s[ni] = (f32x4){0.f, 0.f, 0.f, 0.f};
#pragma unroll
    for (int ni = 0; ni < 4; ++ni) {
      const int krow = ni * 16 + lr;
      const int sw = (krow & 7) << 4;
#pragma unroll
      for (int kf = 0; kf < 2; ++kf) {
        short8 kb =
            *(const short8 *)(Ks + ((krow * 128 + kf * 64 + lq * 16) ^ sw));
        s[ni] =
            __builtin_amdgcn_mfma_f32_16x16x32_bf16(qf[kf], kb, s[ni], 0, 0, 0);
      }
    }

    // fused threefry masks + softmax numerator + dropout -> P via cvt_pk
    const uint32_t colbase = (uint32_t)(kv + lr);
#pragma unroll
    for (int r = 0; r < 4; ++r) {
      float pd[4];
#pragma unroll
      for (int ni = 0; ni < 4; ++ni) {
        const uint32_t ctr = rowflat[r] + colbase + (uint32_t)(ni * 16);
        const bool keep_s = tf_rt(ta.sp, ctr) >= ta.sp_thr;
        const bool keep_d = tf_rt(ta.dp, ctr) >= ta.dp_thr;
        float e = exp_scaled(s[ni][r]);
        float p = keep_s ? e : 0.0f;
        lacc[r] += p;
        pd[ni] = keep_d ? p * (1.0f / 0.9f) : 0.0f;
      }
      const uint32_t u01 = cvt_pk_bf16(pd[0], pd[1]);
      const uint32_t u23 = cvt_pk_bf16(pd[2], pd[3]);
      const int prow = lq * 4 + r;
      const int sw = (prow & 7) << 4;
      uint8_t *rowp = Ps + prow * 128;
      *(ushort *)(rowp + ((lr * 2 + 0) ^ sw)) = (ushort)u01;
      *(ushort *)(rowp + ((lr * 2 + 32) ^ sw)) = (ushort)(u01 >> 16);
      *(ushort *)(rowp + ((lr * 2 + 64) ^ sw)) = (ushort)u23;
      *(ushort *)(rowp + ((lr * 2 + 96) ^ sw)) = (ushort)(u23 >> 16);
    }

#pragma unroll
    for (int kf = 0; kf < 2; ++kf) {
      short8 pa = *(const short8 *)(Ps + ((lr * 128 + kf * 64 + lq * 16) ^
                                          ((lr & 7) << 4)));
#pragma unroll
      for (int nd = 0; nd < 4; ++nd) {
        const int vrow = nd * 16 + lr;
        short8 vb = *(const short8 *)(Vt + ((vrow * 128 + kf * 64 + lq * 16) ^
                                            ((vrow & 7) << 4)));
        o[nd] = __builtin_amdgcn_mfma_f32_16x16x32_bf16(pa, vb, o[nd], 0, 0, 0);
      }
    }

    if (more) STORE(cur ^ 1)
    __syncthreads();
  }
#undef ISSUE
#undef STORE

  float inv[4];
#pragma unroll
  for (int r = 0; r < 4; ++r) {
    float t = lacc[r];
    t += __shfl_xor(t, 1);
    t += __shfl_xor(t, 2);
    t += __shfl_xor(t, 4);
    t += __shfl_xor(t, 8);
    inv[r] = 1.0f / t;
  }
#pragma unroll
  for (int nd = 0; nd < 4; ++nd)
#pragma unroll
    for (int r = 0; r < 4; ++r) {
      const int qrow = qb + w * 16 + lq * 4 + r;
      const size_t idx =
          ((size_t)(b * SQ + qrow)) * DMODEL + h * DK + nd * 16 + lr;
      const float val = o[nd][r] * inv[r];
      const ushort hh = f2bf_rne(val);
      xah[idx] = hh;
      xal[idx] = f2bf_rne(val - bf2f(hh));
    }
}

// ---------------------------------------------------------------------------
extern "C" void kernel_launch(void *const *d_in, const int *in_sizes, int n_in,
                              void *d_out, int out_size, void *d_ws,
                              size_t ws_size, hipStream_t stream) {
  (void)in_sizes; (void)n_in; (void)out_size;
  const float *query = (const float *)d_in[0];
  const float *key_  = (const float *)d_in[1];
  const float *value = (const float *)d_in[2];
  const float *Wq = (const float *)d_in[3];
  const float *bq = (const float *)d_in[4];
  const float *Wk = (const float *)d_in[5];
  const float *bk = (const float *)d_in[6];
  const float *Wv = (const float *)d_in[7];
  const float *bv = (const float *)d_in[8];
  const float *Wo = (const float *)d_in[9];
  const float *bo = (const float *)d_in[10];
  float *out = (float *)d_out;

  const size_t MB = (size_t)1 << 20;
  if (ws_size < 92 * MB) return;

  char *ws = (char *)d_ws;
  ushort *qih = (ushort *)(ws);
  ushort *qil = (ushort *)(ws + 8 * MB);
  ushort *kih = (ushort *)(ws + 16 * MB);
  ushort *kil = (ushort *)(ws + 24 * MB);
  ushort *vih = (ushort *)(ws + 32 * MB);
  ushort *vil = (ushort *)(ws + 40 * MB);
  ushort *Wqh = (ushort *)(ws + 48 * MB);
  ushort *Wql = (ushort *)(ws + 48 * MB + 512 * 1024);
  ushort *Wkh = (ushort *)(ws + 49 * MB);
  ushort *Wkl = (ushort *)(ws + 49 * MB + 512 * 1024);
  ushort *Wvh = (ushort *)(ws + 50 * MB);
  ushort *Wvl = (ushort *)(ws + 50 * MB + 512 * 1024);
  ushort *Woh = (ushort *)(ws + 51 * MB);
  ushort *Wol = (ushort *)(ws + 51 * MB + 512 * 1024);
  ushort *qp  = (ushort *)(ws + 52 * MB);
  ushort *kp  = (ushort *)(ws + 60 * MB);
  ushort *vpt = (ushort *)(ws + 68 * MB);
  ushort *xah = (ushort *)(ws + 76 * MB);
  ushort *xal = (ushort *)(ws + 84 * MB);

  constexpr uint32_t KS2s = SPK.a ^ SPK.b ^ 0x1BD11BDAu;
  constexpr uint32_t KS2d = DPK.a ^ DPK.b ^ 0x1BD11BDAu;
  TfArgs ta = {
      {SPK.a, SPK.b, KS2s + 1u, SPK.a + 2u, SPK.b + 3u, KS2s + 4u, SPK.a + 5u,
       KS2s},
      {DPK.a, DPK.b, KS2d + 1u, DPK.a + 2u, DPK.b + 3u, KS2d + 4u, DPK.a + 5u,
       KS2d},
      SP_THR, DP_THR};

  // q,k,v + all 4 weights split in one launch
  split_all<<<13312, 256, 0, stream>>>(query, key_, value, Wq, Wk, Wv, Wo, qih,
                                       qil, kih, kil, vih, vil, Wqh, Wql, Wkh,
                                       Wkl, Wvh, Wvl, Woh, Wol);

  // Q and K projections fused (BN=32, 2048 blocks total for TLP)
  proj_qk<<<dim3(16, 64, 2), 256, 0, stream>>>(qih, qil, kih, kil, Wqh, Wql,
                                               Wkh, Wkl, bq, bk, qp, kp);

  // V projection -> per-head V^T (BN=32, 1024 blocks)
  proj_v<<<dim3(256, 4), 256, 0, stream>>>(Wvh, Wvl, vih, vil, bv, vpt);

  attn_mfma<<<dim3(SQ / 64, NH, BATCH), 256, 0, stream>>>(qp, kp, vpt, xah,
                                                          xal, ta);

  proj_o<<<dim3(16, 64), 256, 0, stream>>>(xah, xal, Woh, Wol, bo, out);
}

// Round 10
// 701.742 us; speedup vs baseline: 1.0678x; 1.0678x over previous
//
#include <hip/hip_runtime.h>
#include <stdint.h>

#define BATCH  4
#define SQ     2048
#define DMODEL 512
#define NH     8
#define DK     64

typedef __attribute__((ext_vector_type(8))) short short8;
typedef __attribute__((ext_vector_type(4))) float f32x4;

// ---------------- threefry2x32 (JAX-compatible, 20 rounds) ----------------
struct TFK { uint32_t a, b; };
constexpr uint32_t rotl_ce(uint32_t x, int d) {
  return (x << d) | (x >> (32 - d));
}
constexpr TFK tf_ce(uint32_t k0, uint32_t k1, uint32_t x0, uint32_t x1) {
  const uint32_t ks[3] = {k0, k1, k0 ^ k1 ^ 0x1BD11BDAu};
  const int rot[2][4] = {{13, 15, 26, 6}, {17, 29, 16, 24}};
  x0 += k0; x1 += k1;
  for (int c = 0; c < 5; ++c) {
    for (int j = 0; j < 4; ++j) {
      x0 += x1; x1 = rotl_ce(x1, rot[c & 1][j]); x1 ^= x0;
    }
    x0 += ks[(c + 1) % 3];
    x1 += ks[(c + 2) % 3] + (uint32_t)(c + 1);
  }
  return TFK{x0, x1};
}
constexpr TFK SPK = tf_ce(0u, 42u, 0u, 1u);  // fold_in(key(42), 1)
constexpr TFK DPK = tf_ce(0u, 42u, 0u, 2u);  // fold_in(key(42), 2)

#define SP_THR 0x80000200u
#define DP_THR 0x1999A200u

// Key-schedule constants as kernel args (SGPR-resident).
struct TfArgs {
  uint32_t sp[8];
  uint32_t dp[8];
  uint32_t sp_thr, dp_thr;
};

__device__ __forceinline__ void tf_round(uint32_t &x0, uint32_t &x1, int d) {
  x0 += x1;
  x1 = __builtin_amdgcn_alignbit(x1, x1, 32 - d);
  x1 ^= x0;
}
__device__ __forceinline__ void tf_grp(uint32_t &x0, uint32_t &x1,
                                       uint32_t injx1, uint32_t injx0, int d0,
                                       int d1, int d2, int d3) {
  x1 += injx1;
  x0 = x0 + injx0 + x1;
  x1 = __builtin_amdgcn_alignbit(x1, x1, 32 - d0);
  x1 ^= x0;
  tf_round(x0, x1, d1);
  tf_round(x0, x1, d2);
  tf_round(x0, x1, d3);
}
__device__ __forceinline__ uint32_t tf_rt(const uint32_t *__restrict__ c,
                                          uint32_t ctr) {
  uint32_t x1 = c[1] + ctr;
  uint32_t x0 = c[0] + x1;
  x1 = __builtin_amdgcn_alignbit(x1, x1, 19);
  x1 ^= x0;
  tf_round(x0, x1, 15);
  tf_round(x0, x1, 26);
  tf_round(x0, x1, 6);
  tf_grp(x0, x1, c[2], c[1], 17, 29, 16, 24);
  tf_grp(x0, x1, c[3], c[7], 13, 15, 26, 6);
  tf_grp(x0, x1, c[4], c[0], 17, 29, 16, 24);
  tf_grp(x0, x1, c[5], c[1], 13, 15, 26, 6);
  return (x0 + c[7]) ^ (x1 + c[6]);
}

__device__ __forceinline__ ushort f2bf_rne(float f) {
  uint32_t u = __float_as_uint(f);
  return (ushort)((u + 0x7fffu + ((u >> 16) & 1u)) >> 16);
}
__device__ __forceinline__ float bf2f(ushort h) {
  return __uint_as_float((uint32_t)h << 16);
}
__device__ __forceinline__ float exp_scaled(float s) {  // exp(s/8)
#if __has_builtin(__builtin_amdgcn_exp2f)
  return __builtin_amdgcn_exp2f(s * 0.18033688011112042f);
#else
  return __expf(s * 0.125f);
#endif
}
// packed RNE f32->bf16x2 (same rounding as f2bf_rne)
__device__ __forceinline__ uint32_t cvt_pk_bf16(float a, float b) {
  uint32_t r;
  asm("v_cvt_pk_bf16_f32 %0, %1, %2" : "=v"(r) : "v"(a), "v"(b));
  return r;
}

// ---------------- hi/lo split: q,k,v + 4 weights in ONE kernel --------------
__device__ __forceinline__ void split4(const float *__restrict__ src,
                                       ushort *__restrict__ dh,
                                       ushort *__restrict__ dl, size_t base) {
  float4 x = *(const float4 *)(src + base);
  uint32_t h[4], lo[4];
#pragma unroll
  for (int i = 0; i < 4; ++i) {
    float xi = ((const float *)&x)[i];
    ushort hh = f2bf_rne(xi);
    h[i] = hh;
    lo[i] = f2bf_rne(xi - bf2f(hh));
  }
  uint2 ph, pl;
  ph.x = h[0] | (h[1] << 16);  ph.y = h[2] | (h[3] << 16);
  pl.x = lo[0] | (lo[1] << 16); pl.y = lo[2] | (lo[3] << 16);
  *(uint2 *)(dh + base) = ph;
  *(uint2 *)(dl + base) = pl;
}

__global__ __launch_bounds__(256) void split_all(
    const float *__restrict__ q, const float *__restrict__ k,
    const float *__restrict__ v, const float *__restrict__ Wq,
    const float *__restrict__ Wk, const float *__restrict__ Wv,
    const float *__restrict__ Wo, ushort *__restrict__ qh,
    ushort *__restrict__ ql, ushort *__restrict__ kh, ushort *__restrict__ kl,
    ushort *__restrict__ vh, ushort *__restrict__ vl, ushort *__restrict__ Wqh,
    ushort *__restrict__ Wql, ushort *__restrict__ Wkh,
    ushort *__restrict__ Wkl, ushort *__restrict__ Wvh,
    ushort *__restrict__ Wvl, ushort *__restrict__ Woh,
    ushort *__restrict__ Wol) {
  const int bid = blockIdx.x;
  const float *src;
  ushort *dh, *dl;
  uint32_t lb;
  if (bid < 12288) {  // q,k,v: 4096 blocks each
    const int which = bid >> 12;
    lb = bid & 4095;
    src = which == 0 ? q : (which == 1 ? k : v);
    dh = which == 0 ? qh : (which == 1 ? kh : vh);
    dl = which == 0 ? ql : (which == 1 ? kl : vl);
  } else {  // weights: 256 blocks each
    const int t = bid - 12288;
    const int wsel = t >> 8;
    lb = t & 255;
    src = wsel == 0 ? Wq : (wsel == 1 ? Wk : (wsel == 2 ? Wv : Wo));
    dh = wsel == 0 ? Wqh : (wsel == 1 ? Wkh : (wsel == 2 ? Wvh : Woh));
    dl = wsel == 0 ? Wql : (wsel == 1 ? Wkl : (wsel == 2 ? Wvl : Wol));
  }
  const size_t base = ((size_t)lb * 256 + threadIdx.x) * 4;
  split4(src, dh, dl, base);
}

// ---------------- hi/lo bf16 MFMA GEMM core (R8-proven geometry) ------------
// D = A @ B^T (+bias); A [M][512], B [N][512], hi/lo bf16.
// Block: 128 A-rows x 64 B-rows; 4 waves of 32x64 (2x4 16x16 frags).
// MODE 0: fp32 out, bias[col].  MODE 1: bf16 out, bias[col].
// MODE 2: bf16 transposed per-head vpt out, bias[row], via LDS transpose.
template <int MODE>
__device__ __forceinline__ void proj_core(const ushort *__restrict__ Ah,
                                          const ushort *__restrict__ Al,
                                          const ushort *__restrict__ Bh,
                                          const ushort *__restrict__ Bl,
                                          const float *__restrict__ bias,
                                          void *__restrict__ Yv) {
  __shared__ ushort Tt[MODE == 2 ? 128 * 72 : 1];
  const int tid = threadIdx.x;
  const int w = tid >> 6, l = tid & 63;
  const int lr = l & 15, lq = l >> 4;
  const int am = blockIdx.y * 128 + w * 32;
  const int bn = blockIdx.x * 64;
  f32x4 acc[2][4];
#pragma unroll
  for (int i = 0; i < 2; ++i)
#pragma unroll
    for (int j = 0; j < 4; ++j) acc[i][j] = (f32x4){0.f, 0.f, 0.f, 0.f};

#pragma unroll 2
  for (int k0 = 0; k0 < DMODEL; k0 += 32) {
    short8 ah[2], al[2], bh[4], bl[4];
#pragma unroll
    for (int mf = 0; mf < 2; ++mf) {
      const size_t off = (size_t)(am + mf * 16 + lr) * DMODEL + k0 + lq * 8;
      ah[mf] = *(const short8 *)(Ah + off);
      al[mf] = *(const short8 *)(Al + off);
    }
#pragma unroll
    for (int nf = 0; nf < 4; ++nf) {
      const size_t off = (size_t)(bn + nf * 16 + lr) * DMODEL + k0 + lq * 8;
      bh[nf] = *(const short8 *)(Bh + off);
      bl[nf] = *(const short8 *)(Bl + off);
    }
#pragma unroll
    for (int mf = 0; mf < 2; ++mf)
#pragma unroll
      for (int nf = 0; nf < 4; ++nf) {
        acc[mf][nf] = __builtin_amdgcn_mfma_f32_16x16x32_bf16(
            ah[mf], bh[nf], acc[mf][nf], 0, 0, 0);
        acc[mf][nf] = __builtin_amdgcn_mfma_f32_16x16x32_bf16(
            ah[mf], bl[nf], acc[mf][nf], 0, 0, 0);
        acc[mf][nf] = __builtin_amdgcn_mfma_f32_16x16x32_bf16(
            al[mf], bh[nf], acc[mf][nf], 0, 0, 0);
      }
  }

  if (MODE == 2) {
#pragma unroll
    for (int mf = 0; mf < 2; ++mf)
#pragma unroll
      for (int nf = 0; nf < 4; ++nf) {
        const int gn2 = am + mf * 16 + lq * 4;
#pragma unroll
        for (int r = 0; r < 4; ++r) {
          const int featl = (w * 32 + mf * 16 + lq * 4 + r);
          Tt[featl * 72 + nf * 16 + lr] =
              f2bf_rne(acc[mf][nf][r] + bias[gn2 + r]);
        }
      }
    __syncthreads();
    ushort *Y = (ushort *)Yv;
    const int feat = tid >> 1, half = tid & 1;
    const int gfeat = blockIdx.y * 128 + feat;
    const int bn2 = blockIdx.x * 64;
    const int bcol = bn2 >> 11, scol = (bn2 & 2047) + half * 32;
    ushort *dst = Y + ((size_t)(bcol * DMODEL + gfeat)) * SQ + scol;
    const ushort *srcp = &Tt[feat * 72 + half * 32];
#pragma unroll
    for (int j = 0; j < 4; ++j)
      *(uint4 *)(dst + j * 8) = *(const uint4 *)(srcp + j * 8);
  } else {
#pragma unroll
    for (int mf = 0; mf < 2; ++mf)
#pragma unroll
      for (int nf = 0; nf < 4; ++nf) {
        const int gn = bn + nf * 16 + lr;
        const float bb = bias[gn];
        if (MODE == 0) {
          float *Y = (float *)Yv;
#pragma unroll
          for (int r = 0; r < 4; ++r) {
            const int gm = am + mf * 16 + lq * 4 + r;
            Y[(size_t)gm * DMODEL + gn] = acc[mf][nf][r] + bb;
          }
        } else {
          ushort *Y = (ushort *)Yv;
#pragma unroll
          for (int r = 0; r < 4; ++r) {
            const int gm = am + mf * 16 + lq * 4 + r;
            Y[(size_t)gm * DMODEL + gn] = f2bf_rne(acc[mf][nf][r] + bb);
          }
        }
      }
  }
}

// Q and K projections fused via blockIdx.z. Grid (8, 64, 2).
__global__ __launch_bounds__(256) void proj_qk(
    const ushort *__restrict__ qih, const ushort *__restrict__ qil,
    const ushort *__restrict__ kih, const ushort *__restrict__ kil,
    const ushort *__restrict__ Wqh, const ushort *__restrict__ Wql,
    const ushort *__restrict__ Wkh, const ushort *__restrict__ Wkl,
    const float *__restrict__ bq, const float *__restrict__ bk,
    ushort *__restrict__ qp, ushort *__restrict__ kp) {
  if (blockIdx.z == 0)
    proj_core<1>(qih, qil, Wqh, Wql, bq, qp);
  else
    proj_core<1>(kih, kil, Wkh, Wkl, bk, kp);
}

// V projection -> per-head V^T (A = Wv feats, B = value rows). Grid (128, 4).
__global__ __launch_bounds__(256) void proj_v(
    const ushort *__restrict__ Wvh, const ushort *__restrict__ Wvl,
    const ushort *__restrict__ vih, const ushort *__restrict__ vil,
    const float *__restrict__ bv, ushort *__restrict__ vpt) {
  proj_core<2>(Wvh, Wvl, vih, vil, bv, vpt);
}

// Output projection (fp32 out). Grid (8, 64).
__global__ __launch_bounds__(256) void proj_o(
    const ushort *__restrict__ xah, const ushort *__restrict__ xal,
    const ushort *__restrict__ Woh, const ushort *__restrict__ Wol,
    const float *__restrict__ bo, float *__restrict__ out) {
  proj_core<0>(xah, xal, Woh, Wol, bo, out);
}

// ---------------- MFMA attention, fused masks, double-buffered staging ------
__global__ __launch_bounds__(256, 4) void attn_mfma(
    const ushort *__restrict__ qp, const ushort *__restrict__ kp,
    const ushort *__restrict__ vpt, ushort *__restrict__ xah,
    ushort *__restrict__ xal, TfArgs ta) {
  __shared__ __align__(16) uint8_t lds[40960];
  const int b = blockIdx.z, h = blockIdx.y;
  const int qb = blockIdx.x * 64;
  const int tid = threadIdx.x;
  const int w = tid >> 6, l = tid & 63;
  const int lr = l & 15, lq = l >> 4;
  uint8_t *Ps = lds + 32768 + w * 2048;
  const int bh = b * NH + h;

  short8 qf[2];
  {
    const int qrow = qb + w * 16 + lr;
    const ushort *qrowp = qp + ((size_t)(b * SQ + qrow)) * DMODEL + h * DK;
    qf[0] = *(const short8 *)(qrowp + lq * 8);
    qf[1] = *(const short8 *)(qrowp + 32 + lq * 8);
  }
  f32x4 o[4];
  f32x4 lacc;
#pragma unroll
  for (int nd = 0; nd < 4; ++nd) o[nd] = (f32x4){0.f, 0.f, 0.f, 0.f};
  lacc = (f32x4){0.f, 0.f, 0.f, 0.f};

  uint32_t rowflat[4];
#pragma unroll
  for (int r = 0; r < 4; ++r)
    rowflat[r] = ((uint32_t)(bh * SQ + qb + w * 16 + lq * 4 + r)) << 11;

  const int srow = tid >> 2;
  const int sc0 = (tid & 3) * 2;
  const int ssw = (srow & 7) << 4;
  const ushort *kbase =
      kp + ((size_t)(b * SQ) + srow) * DMODEL + h * DK + sc0 * 8;
  const ushort *vbase = vpt + ((size_t)(bh * DK + srow)) * SQ + sc0 * 8;
  const int la0 = (srow * 128 + sc0 * 16) ^ ssw;
  const int la1 = (srow * 128 + (sc0 + 1) * 16) ^ ssw;

  uint4 kr0, kr1, vr0, vr1;
#define ISSUE(kv_)                                            \
  {                                                           \
    const ushort *ks_ = kbase + (size_t)(kv_)*DMODEL;         \
    kr0 = *(const uint4 *)ks_;                                \
    kr1 = *(const uint4 *)(ks_ + 8);                          \
    const ushort *vs_ = vbase + (kv_);                        \
    vr0 = *(const uint4 *)vs_;                                \
    vr1 = *(const uint4 *)(vs_ + 8);                          \
  }
#define STORE(buf_)                                           \
  {                                                           \
    uint8_t *Kb_ = lds + (buf_)*8192;                         \
    uint8_t *Vb_ = lds + 16384 + (buf_)*8192;                 \
    *(uint4 *)(Kb_ + la0) = kr0;                              \
    *(uint4 *)(Kb_ + la1) = kr1;                              \
    *(uint4 *)(Vb_ + la0) = vr0;                              \
    *(uint4 *)(Vb_ + la1) = vr1;                              \
  }

  ISSUE(0)
  STORE(0)
  __syncthreads();

  for (int kv = 0; kv < SQ; kv += 64) {
    const int cur = (kv >> 6) & 1;
    uint8_t *Ks = lds + cur * 8192;
    uint8_t *Vt = lds + 16384 + cur * 8192;
    const bool more = (kv + 64) < SQ;
    if (more) ISSUE(kv + 64)

    f32x4 s[4];
#pragma unroll
    for (int ni = 0; ni < 4; ++ni) s[ni] = (f32x4){0.f, 0.f, 0.f, 0.f};
#pragma unroll
    for (int ni = 0; ni < 4; ++ni) {
      const int krow = ni * 16 + lr;
      const int sw = (krow & 7) << 4;
#pragma unroll
      for (int kf = 0; kf < 2; ++kf) {
        short8 kb =
            *(const short8 *)(Ks + ((krow * 128 + kf * 64 + lq * 16) ^ sw));
        s[ni] =
            __builtin_amdgcn_mfma_f32_16x16x32_bf16(qf[kf], kb, s[ni], 0, 0, 0);
      }
    }

    // fused threefry masks + softmax numerator + dropout -> P via cvt_pk
    const uint32_t colbase = (uint32_t)(kv + lr);
#pragma unroll
    for (int r = 0; r < 4; ++r) {
      float pd[4];
#pragma unroll
      for (int ni = 0; ni < 4; ++ni) {
        const uint32_t ctr = rowflat[r] + colbase + (uint32_t)(ni * 16);
        const bool keep_s = tf_rt(ta.sp, ctr) >= ta.sp_thr;
        const bool keep_d = tf_rt(ta.dp, ctr) >= ta.dp_thr;
        float e = exp_scaled(s[ni][r]);
        float p = keep_s ? e : 0.0f;
        lacc[r] += p;
        pd[ni] = keep_d ? p * (1.0f / 0.9f) : 0.0f;
      }
      const uint32_t u01 = cvt_pk_bf16(pd[0], pd[1]);
      const uint32_t u23 = cvt_pk_bf16(pd[2], pd[3]);
      const int prow = lq * 4 + r;
      const int sw = (prow & 7) << 4;
      uint8_t *rowp = Ps + prow * 128;
      *(ushort *)(rowp + ((lr * 2 + 0) ^ sw)) = (ushort)u01;
      *(ushort *)(rowp + ((lr * 2 + 32) ^ sw)) = (ushort)(u01 >> 16);
      *(ushort *)(rowp + ((lr * 2 + 64) ^ sw)) = (ushort)u23;
      *(ushort *)(rowp + ((lr * 2 + 96) ^ sw)) = (ushort)(u23 >> 16);
    }

#pragma unroll
    for (int kf = 0; kf < 2; ++kf) {
      short8 pa = *(const short8 *)(Ps + ((lr * 128 + kf * 64 + lq * 16) ^
                                          ((lr & 7) << 4)));
#pragma unroll
      for (int nd = 0; nd < 4; ++nd) {
        const int vrow = nd * 16 + lr;
        short8 vb = *(const short8 *)(Vt + ((vrow * 128 + kf * 64 + lq * 16) ^
                                            ((vrow & 7) << 4)));
        o[nd] = __builtin_amdgcn_mfma_f32_16x16x32_bf16(pa, vb, o[nd], 0, 0, 0);
      }
    }

    if (more) STORE(cur ^ 1)
    __syncthreads();
  }
#undef ISSUE
#undef STORE

  float inv[4];
#pragma unroll
  for (int r = 0; r < 4; ++r) {
    float t = lacc[r];
    t += __shfl_xor(t, 1);
    t += __shfl_xor(t, 2);
    t += __shfl_xor(t, 4);
    t += __shfl_xor(t, 8);
    inv[r] = 1.0f / t;
  }
#pragma unroll
  for (int nd = 0; nd < 4; ++nd)
#pragma unroll
    for (int r = 0; r < 4; ++r) {
      const int qrow = qb + w * 16 + lq * 4 + r;
      const size_t idx =
          ((size_t)(b * SQ + qrow)) * DMODEL + h * DK + nd * 16 + lr;
      const float val = o[nd][r] * inv[r];
      const ushort hh = f2bf_rne(val);
      xah[idx] = hh;
      xal[idx] = f2bf_rne(val - bf2f(hh));
    }
}

// ---------------------------------------------------------------------------
extern "C" void kernel_launch(void *const *d_in, const int *in_sizes, int n_in,
                              void *d_out, int out_size, void *d_ws,
                              size_t ws_size, hipStream_t stream) {
  (void)in_sizes; (void)n_in; (void)out_size;
  const float *query = (const float *)d_in[0];
  const float *key_  = (const float *)d_in[1];
  const float *value = (const float *)d_in[2];
  const float *Wq = (const float *)d_in[3];
  const float *bq = (const float *)d_in[4];
  const float *Wk = (const float *)d_in[5];
  const float *bk = (const float *)d_in[6];
  const float *Wv = (const float *)d_in[7];
  const float *bv = (const float *)d_in[8];
  const float *Wo = (const float *)d_in[9];
  const float *bo = (const float *)d_in[10];
  float *out = (float *)d_out;

  const size_t MB = (size_t)1 << 20;
  if (ws_size < 92 * MB) return;

  char *ws = (char *)d_ws;
  ushort *qih = (ushort *)(ws);
  ushort *qil = (ushort *)(ws + 8 * MB);
  ushort *kih = (ushort *)(ws + 16 * MB);
  ushort *kil = (ushort *)(ws + 24 * MB);
  ushort *vih = (ushort *)(ws + 32 * MB);
  ushort *vil = (ushort *)(ws + 40 * MB);
  ushort *Wqh = (ushort *)(ws + 48 * MB);
  ushort *Wql = (ushort *)(ws + 48 * MB + 512 * 1024);
  ushort *Wkh = (ushort *)(ws + 49 * MB);
  ushort *Wkl = (ushort *)(ws + 49 * MB + 512 * 1024);
  ushort *Wvh = (ushort *)(ws + 50 * MB);
  ushort *Wvl = (ushort *)(ws + 50 * MB + 512 * 1024);
  ushort *Woh = (ushort *)(ws + 51 * MB);
  ushort *Wol = (ushort *)(ws + 51 * MB + 512 * 1024);
  ushort *qp  = (ushort *)(ws + 52 * MB);
  ushort *kp  = (ushort *)(ws + 60 * MB);
  ushort *vpt = (ushort *)(ws + 68 * MB);
  ushort *xah = (ushort *)(ws + 76 * MB);
  ushort *xal = (ushort *)(ws + 84 * MB);

  constexpr uint32_t KS2s = SPK.a ^ SPK.b ^ 0x1BD11BDAu;
  constexpr uint32_t KS2d = DPK.a ^ DPK.b ^ 0x1BD11BDAu;
  TfArgs ta = {
      {SPK.a, SPK.b, KS2s + 1u, SPK.a + 2u, SPK.b + 3u, KS2s + 4u, SPK.a + 5u,
       KS2s},
      {DPK.a, DPK.b, KS2d + 1u, DPK.a + 2u, DPK.b + 3u, KS2d + 4u, DPK.a + 5u,
       KS2d},
      SP_THR, DP_THR};

  // q,k,v + all 4 weights split in one launch
  split_all<<<13312, 256, 0, stream>>>(query, key_, value, Wq, Wk, Wv, Wo, qih,
                                       qil, kih, kil, vih, vil, Wqh, Wql, Wkh,
                                       Wkl, Wvh, Wvl, Woh, Wol);

  // Q and K projections fused (R8-proven geometry: BN=64)
  proj_qk<<<dim3(8, 64, 2), 256, 0, stream>>>(qih, qil, kih, kil, Wqh, Wql,
                                              Wkh, Wkl, bq, bk, qp, kp);

  // V projection -> per-head V^T
  proj_v<<<dim3(128, 4), 256, 0, stream>>>(Wvh, Wvl, vih, vil, bv, vpt);

  attn_mfma<<<dim3(SQ / 64, NH, BATCH), 256, 0, stream>>>(qp, kp, vpt, xah,
                                                          xal, ta);

  proj_o<<<dim3(8, 64), 256, 0, stream>>>(xah, xal, Woh, Wol, bo, out);
}